// Round 12
// baseline (243.137 us; speedup 1.0000x reference)
//
#include <hip/hip_runtime.h>
#include <hip/hip_fp16.h>

// Problem constants: B=2, T=32, H=64, W=64, C=64, KT=5, K=7. Circular dims pow2 -> & masks.
// Intermediates are CHANNEL-MAJOR: uint array [pair=c/2][b][t][h][w], pair stride 262144 uints.
#define NELEM 16777216

typedef _Float16 f16x8 __attribute__((ext_vector_type(8)));
typedef _Float16 h2v  __attribute__((ext_vector_type(2)));
typedef float f32x4 __attribute__((ext_vector_type(4)));

// packed f16 fma, tap in SGPR (VOP3P allows 1 SGPR source)
static __device__ __forceinline__ void pk_fma_sv(uint& d, uint a_s, uint b_v) {
    asm("v_pk_fma_f16 %0, %1, %2, %0" : "+v"(d) : "s"(a_s), "v"(b_v));
}

// ---------------- fused dual projection GEMM (MFMA f16, channel-major out) ----------------
__global__ __launch_bounds__(256) void proj2_kernel(
    const float* __restrict__ x,
    const float* __restrict__ wg, const float* __restrict__ bg,
    const float* __restrict__ wh, const float* __restrict__ bh,
    uint* __restrict__ pg, uint* __restrict__ ph)
{
    __shared__ __align__(16) _Float16 sX[128 * 64];
    __shared__ __align__(16) _Float16 sWT[2][64 * 64];
    const int tid = threadIdx.x;
    const int row0 = (int)blockIdx.x * 128;

    #pragma unroll
    for (int kci = 0; kci < 4; ++kci) {
        const int chunk = tid + kci * 256;
        const int r = chunk >> 3, q = chunk & 7;
        const float* gp = x + (long long)(row0 + r) * 64 + q * 8;
        const float4 v0 = *reinterpret_cast<const float4*>(gp);
        const float4 v1 = *reinterpret_cast<const float4*>(gp + 4);
        f16x8 hv;
        hv[0] = (_Float16)v0.x; hv[1] = (_Float16)v0.y; hv[2] = (_Float16)v0.z; hv[3] = (_Float16)v0.w;
        hv[4] = (_Float16)v1.x; hv[5] = (_Float16)v1.y; hv[6] = (_Float16)v1.z; hv[7] = (_Float16)v1.w;
        *reinterpret_cast<f16x8*>(&sX[r * 64 + ((q ^ (r & 7)) * 8)]) = hv;
    }
    {
        const int d = tid & 63;
        const int cb = (tid >> 6) * 16;
        #pragma unroll
        for (int i = 0; i < 16; ++i) {
            const int c = cb + i;
            const int off = d * 64 + (((c >> 3) ^ (d & 7)) * 8) + (c & 7);
            sWT[0][off] = (_Float16)wg[c * 64 + d];
            sWT[1][off] = (_Float16)wh[c * 64 + d];
        }
    }
    __syncthreads();

    const int wv = tid >> 6, lm = tid & 15, lg = (tid & 63) >> 4;
    f16x8 bf[2][4][2];
    #pragma unroll
    for (int nt = 0; nt < 4; ++nt) {
        const int d = nt * 16 + lm;
        #pragma unroll
        for (int s = 0; s < 2; ++s) {
            const int off = d * 64 + (((s * 4 + lg) ^ (d & 7)) * 8);
            bf[0][nt][s] = *reinterpret_cast<const f16x8*>(&sWT[0][off]);
            bf[1][nt][s] = *reinterpret_cast<const f16x8*>(&sWT[1][off]);
        }
    }
    f32x4 acc[2][2][4];
    #pragma unroll
    for (int m = 0; m < 2; ++m)
        #pragma unroll
        for (int mt = 0; mt < 2; ++mt)
            #pragma unroll
            for (int nt = 0; nt < 4; ++nt)
                acc[m][mt][nt] = (f32x4){0.f, 0.f, 0.f, 0.f};

    #pragma unroll
    for (int mt = 0; mt < 2; ++mt) {
        const int r = wv * 32 + mt * 16 + lm;
        const f16x8 a0 = *reinterpret_cast<const f16x8*>(&sX[r * 64 + ((lg ^ (r & 7)) * 8)]);
        const f16x8 a1 = *reinterpret_cast<const f16x8*>(&sX[r * 64 + (((4 + lg) ^ (r & 7)) * 8)]);
        #pragma unroll
        for (int nt = 0; nt < 4; ++nt) {
            acc[0][mt][nt] = __builtin_amdgcn_mfma_f32_16x16x32_f16(a0, bf[0][nt][0], acc[0][mt][nt], 0, 0, 0);
            acc[0][mt][nt] = __builtin_amdgcn_mfma_f32_16x16x32_f16(a1, bf[0][nt][1], acc[0][mt][nt], 0, 0, 0);
            acc[1][mt][nt] = __builtin_amdgcn_mfma_f32_16x16x32_f16(a0, bf[1][nt][0], acc[1][mt][nt], 0, 0, 0);
            acc[1][mt][nt] = __builtin_amdgcn_mfma_f32_16x16x32_f16(a1, bf[1][nt][1], acc[1][mt][nt], 0, 0, 0);
        }
    }
    // epilogue: pair lanes (lm, lm^1) via shfl, even lane stores uint4 (4 rows) channel-major
    #pragma unroll
    for (int nt = 0; nt < 4; ++nt) {
        const int col = nt * 16 + lm;
        const int pr  = col >> 1;
        const float bgv = bg[col], bhv = bh[col];
        #pragma unroll
        for (int mt = 0; mt < 2; ++mt) {
            const int rb = row0 + wv * 32 + mt * 16 + lg * 4;
            uint pk0[4], pk1[4];
            #pragma unroll
            for (int i = 0; i < 4; ++i) {
                const float v0 = acc[0][mt][nt][i] + bgv;
                const float p0 = __shfl_xor(v0, 1);
                const float v1 = acc[1][mt][nt][i] + bhv;
                const float p1 = __shfl_xor(v1, 1);
                h2v a, c;
                a[0] = (_Float16)((lm & 1) ? p0 : v0); a[1] = (_Float16)((lm & 1) ? v0 : p0);
                c[0] = (_Float16)((lm & 1) ? p1 : v1); c[1] = (_Float16)((lm & 1) ? v1 : p1);
                pk0[i] = __builtin_bit_cast(uint, a);
                pk1[i] = __builtin_bit_cast(uint, c);
            }
            if (!(lm & 1)) {
                *reinterpret_cast<uint4*>(pg + pr * 262144 + rb) = make_uint4(pk0[0], pk0[1], pk0[2], pk0[3]);
                *reinterpret_cast<uint4*>(ph + pr * 262144 + rb) = make_uint4(pk1[0], pk1[1], pk1[2], pk1[3]);
            }
        }
    }
}

// ---------------- tap pre-convert: f32 kernels -> packed f16 pair table ----------------
// taps[((mat*32 + p)*35 + kt*7+kh)*8 + kw], kw=7 zero-padded
__global__ __launch_bounds__(256) void tapconv_kernel(
    const float* __restrict__ gk, const float* __restrict__ hk, uint* __restrict__ taps)
{
    const int i = blockIdx.x * 256 + threadIdx.x;   // [0, 17920)
    if (i >= 17920) return;
    const int kw = i & 7;
    int r = i >> 3;
    const int kth = r % 35;  r /= 35;
    const int p = r & 31;
    const int mat = r >> 5;
    if (kw >= 7) { taps[i] = 0u; return; }
    const float* K = mat ? hk : gk;
    const int tap = kth * 7 + kw;
    h2v hv;
    hv[0] = (_Float16)K[(2 * p) * 245 + tap];
    hv[1] = (_Float16)K[(2 * p + 1) * 245 + tap];
    taps[i] = __builtin_bit_cast(uint, hv);
}

// ---------------- depthwise circular 3D conv: LDS slab staging, channel-major ----------------
// Wave = one channel-pair x 16h x full-W(64) tile; lane (iy in [0,4), ix in [0,16))
// computes 4h x 4w h2 outputs. Per kt: stage the 22-row x 64-uint slab (rows h0-3..h0+18,
// circular) into wave-private LDS (6 uint4 loads + 6 ds_write_b128), then read the sliding
// windows from LDS -> global operand traffic per wave per kt drops 30KB -> 6KB; the 2.5x
// lane-overlap redundancy is absorbed by the LDS pipe. Row stride 66 dwords: 4*66 % 32 = 8,
// so the four iy-groups start at banks {0,8,16,24} -> conflict-minimal b128 reads.
// Taps in SGPRs (uniform loads). Wave-synchronous DS ordering: zero barriers.
// LDS/block = 4 waves * 6336B = 25.3KB -> 6 blocks/CU = 24 waves/CU.
__global__ __launch_bounds__(256) void conv3d_dual_kernel(
    const uint* __restrict__ inG, uint* __restrict__ outG,
    const uint* __restrict__ inH, uint* __restrict__ outH,
    const uint* __restrict__ taps)
{
    __shared__ __align__(16) uint slabAll[4 * 1584];   // 25344 B

    const int bid = (int)blockIdx.x;                // 0..4095
    const int l = ((bid & 7) << 9) | (bid >> 3);    // chunked XCD swizzle
    const int hb   = l & 3;
    const int t    = (l >> 2) & 31;
    const int pgrp = (l >> 7) & 7;
    const int b    = (l >> 10) & 1;
    const int mat  = (l >> 11) & 1;
    const int wave = threadIdx.x >> 6;
    const int lane = threadIdx.x & 63;
    const int h0 = hb * 16;
    const int pair = pgrp * 4 + wave;

    const uint* in = mat ? inH : inG;
    uint* out      = mat ? outH : outG;
    uint* slab = slabAll + wave * 1584;

    const int iy = lane >> 4, ix = lane & 15;

    // wave-uniform SGPR bases
    const int tapOff = __builtin_amdgcn_readfirstlane((mat * 32 + pair) * 280);
    const uint* tb = taps + tapOff;
    const int pbOff = __builtin_amdgcn_readfirstlane(pair * 262144 + b * 131072);

    // staging addresses: inst i stages slab row 4i + (lane>>4), chunk c4 = lane&15
    const int srow = lane >> 4;
    const int sc4  = lane & 15;
    int gsrc[6], ldst[6];
    #pragma unroll
    for (int i = 0; i < 6; ++i) {
        const int r = 4 * i + srow;                 // 0..23 (22 used)
        const int gh = (h0 - 3 + r) & 63;
        gsrc[i] = gh * 64 + 4 * sc4;
        ldst[i] = r * 66 + 4 * sc4;
    }

    // read window cols (full-row circular, 4-aligned -> uint4 never splits)
    int colu[3];
    #pragma unroll
    for (int m = 0; m < 3; ++m) colu[m] = (4 * ix - 4 + 4 * m) & 63;

    uint tot[4][4];
    #pragma unroll
    for (int o = 0; o < 4; ++o)
        #pragma unroll
        for (int j = 0; j < 4; ++j) tot[o][j] = 0u;

    #pragma unroll 1
    for (int kt = 0; kt < 5; ++kt) {
        const int tin = (t - kt + 2) & 31;
        const uint* pin = in + pbOff + tin * 4096;  // SGPR base
        const uint* tkt = tb + kt * 56;

        uint kv[7][8];                              // SGPR tap block (uniform loads)
        #pragma unroll
        for (int kh = 0; kh < 7; ++kh)
            #pragma unroll
            for (int i2 = 0; i2 < 8; ++i2) kv[kh][i2] = tkt[kh * 8 + i2];

        // stage slab: 6 global uint4 loads -> 6 ds_write_b128 (wave-private, no barrier)
        uint4 st[6];
        #pragma unroll
        for (int i = 0; i < 6; ++i)
            st[i] = *reinterpret_cast<const uint4*>(pin + gsrc[i]);
        #pragma unroll
        for (int i = 0; i < 6; ++i)
            *reinterpret_cast<uint4*>(slab + ldst[i]) = st[i];

        #pragma unroll
        for (int rr = 0; rr < 10; ++rr) {
            const uint* rp = slab + (4 * iy + rr) * 66;
            uint row[12];
            #pragma unroll
            for (int m = 0; m < 3; ++m) {
                const uint4 v = *reinterpret_cast<const uint4*>(rp + colu[m]);
                row[4 * m]     = v.x; row[4 * m + 1] = v.y;
                row[4 * m + 2] = v.z; row[4 * m + 3] = v.w;
            }
            #pragma unroll
            for (int kw = 0; kw < 7; ++kw)
                #pragma unroll
                for (int o = 0; o < 4; ++o) {
                    const int kh = o + 6 - rr;
                    if (kh < 0 || kh > 6) continue;
                    #pragma unroll
                    for (int j = 0; j < 4; ++j)
                        pk_fma_sv(tot[o][j], kv[kh][kw], row[j + 7 - kw]);
                }
        }
    }

    uint* ob = out + pair * 262144 + (b * 32 + t) * 4096 + h0 * 64;
    #pragma unroll
    for (int o = 0; o < 4; ++o)
        *reinterpret_cast<uint4*>(ob + (4 * iy + o) * 64 + 4 * ix) =
            make_uint4(tot[o][0], tot[o][1], tot[o][2], tot[o][3]);
}

// ---------------- minGRU scan over T (f32 math, channel-major h2 I/O) ----------------
__global__ __launch_bounds__(256) void scan_kernel(
    const uint* __restrict__ gs, const uint* __restrict__ hs, uint* __restrict__ hout)
{
    const int tid = blockIdx.x * 256 + threadIdx.x;    // 0..262143
    const int base = (tid >> 12) * 131072 + (tid & 4095);
    float h0 = 0.f, h1 = 0.f;
    for (int t = 0; t < 32; ++t) {
        const int a = base + t * 4096;
        const float2 g  = __half22float2(__builtin_bit_cast(__half2, gs[a]));
        const float2 hv = __half22float2(__builtin_bit_cast(__half2, hs[a]));
        const float z0 = 1.f / (1.f + __expf(-g.x));
        const float z1 = 1.f / (1.f + __expf(-g.y));
        h0 = fmaf(1.f - z0, h0, z0 * fmaf(hv.x, hv.x, 1e-6f));
        h1 = fmaf(1.f - z1, h1, z1 * fmaf(hv.y, hv.y, 1e-6f));
        hout[a] = __builtin_bit_cast(uint, __floats2half2_rn(h0, h1));
    }
}

// ---------------- output GEMM (MFMA f16, channel-major in, f32 row-major out) ----------------
__global__ __launch_bounds__(256) void outgemm_kernel(
    const uint* __restrict__ hin, const float* __restrict__ w,
    const float* __restrict__ bias, float* __restrict__ out)
{
    __shared__ __align__(16) uint sXu[128 * 36];        // rows x 32 pairs (stride 36: 16B-aligned)
    __shared__ __align__(16) _Float16 sWT[64 * 64];
    const int tid = threadIdx.x;
    const int row0 = (int)blockIdx.x * 128;

    {   // stage 128 rows x 32 pairs from channel-major
        const int pr = tid >> 3, k = tid & 7;
        const uint* src = hin + pr * 262144 + row0 + k * 16;
        #pragma unroll
        for (int q = 0; q < 4; ++q) {
            const uint4 v = *reinterpret_cast<const uint4*>(src + q * 4);
            sXu[(k * 16 + q * 4 + 0) * 36 + pr] = v.x;
            sXu[(k * 16 + q * 4 + 1) * 36 + pr] = v.y;
            sXu[(k * 16 + q * 4 + 2) * 36 + pr] = v.z;
            sXu[(k * 16 + q * 4 + 3) * 36 + pr] = v.w;
        }
    }
    {
        const int d = tid & 63;
        const int cb = (tid >> 6) * 16;
        #pragma unroll
        for (int i = 0; i < 16; ++i) {
            const int c = cb + i;
            sWT[d * 64 + (((c >> 3) ^ (d & 7)) * 8) + (c & 7)] = (_Float16)w[c * 64 + d];
        }
    }
    __syncthreads();

    const int wv = tid >> 6, lm = tid & 15, lg = (tid & 63) >> 4;
    f16x8 bf[4][2];
    #pragma unroll
    for (int nt = 0; nt < 4; ++nt) {
        const int d = nt * 16 + lm;
        #pragma unroll
        for (int s = 0; s < 2; ++s)
            bf[nt][s] = *reinterpret_cast<const f16x8*>(&sWT[d * 64 + (((s * 4 + lg) ^ (d & 7)) * 8)]);
    }
    f32x4 acc[2][4];
    #pragma unroll
    for (int mt = 0; mt < 2; ++mt)
        #pragma unroll
        for (int nt = 0; nt < 4; ++nt)
            acc[mt][nt] = (f32x4){0.f, 0.f, 0.f, 0.f};

    #pragma unroll
    for (int mt = 0; mt < 2; ++mt) {
        const int r = wv * 32 + mt * 16 + lm;
        const f16x8 a0 = *reinterpret_cast<const f16x8*>(&sXu[r * 36 + lg * 4]);
        const f16x8 a1 = *reinterpret_cast<const f16x8*>(&sXu[r * 36 + 16 + lg * 4]);
        #pragma unroll
        for (int nt = 0; nt < 4; ++nt) {
            acc[mt][nt] = __builtin_amdgcn_mfma_f32_16x16x32_f16(a0, bf[nt][0], acc[mt][nt], 0, 0, 0);
            acc[mt][nt] = __builtin_amdgcn_mfma_f32_16x16x32_f16(a1, bf[nt][1], acc[mt][nt], 0, 0, 0);
        }
    }
    #pragma unroll
    for (int nt = 0; nt < 4; ++nt) {
        const int col = nt * 16 + lm;
        const float bv = bias[col];
        #pragma unroll
        for (int mt = 0; mt < 2; ++mt) {
            const long long rb = row0 + wv * 32 + mt * 16 + lg * 4;
            #pragma unroll
            for (int i = 0; i < 4; ++i)
                out[(rb + i) * 64 + col] = acc[mt][nt][i] + bv;
        }
    }
}

extern "C" void kernel_launch(void* const* d_in, const int* in_sizes, int n_in,
                              void* d_out, int out_size, void* d_ws, size_t ws_size,
                              hipStream_t stream)
{
    const float* x  = (const float*)d_in[0];
    const float* gw = (const float*)d_in[1];
    const float* gb = (const float*)d_in[2];
    const float* hw = (const float*)d_in[3];
    const float* hb = (const float*)d_in[4];
    const float* gk = (const float*)d_in[5];
    const float* hk = (const float*)d_in[6];
    const float* ow = (const float*)d_in[7];
    const float* ob = (const float*)d_in[8];

    uint* W1 = (uint*)d_ws;                  // 33.5 MB each (channel-major h2)
    uint* W2 = W1 + NELEM / 2;
    uint* W3 = W2 + NELEM / 2;
    uint* taps = W3 + NELEM / 2;             // 71.7 KB tap table
    uint* Dsc = (uint*)d_out;                // hidden_spatial scratch (first 33.5MB of d_out)

    // 0) tap table
    tapconv_kernel<<<70, 256, 0, stream>>>(gk, hk, taps);
    // 1) proj: x -> W1 (gate_proj cm), W2 (hidden_proj cm)
    proj2_kernel<<<2048, 256, 0, stream>>>(x, gw, gb, hw, hb, W1, W2);
    // 2+3) dual conv (LDS slab): W1 -> W3 (gate_sp), W2 -> Dsc (hidden_sp)
    conv3d_dual_kernel<<<4096, 256, 0, stream>>>(W1, W3, W2, Dsc, taps);
    // 4) scan: (W3, Dsc) -> W1 (h, cm)
    scan_kernel<<<1024, 256, 0, stream>>>(W3, Dsc, W1);
    // 5) out GEMM: W1 -> d_out (f32 row-major, overwrites scratch)
    outgemm_kernel<<<2048, 256, 0, stream>>>(W1, ow, ob, (float*)d_out);
}

// Round 13
// 238.968 us; speedup vs baseline: 1.0174x; 1.0174x over previous
//
#include <hip/hip_runtime.h>
#include <hip/hip_fp16.h>

// Problem constants: B=2, T=32, H=64, W=64, C=64, KT=5, K=7. Circular dims pow2 -> & masks.
// Intermediates are CHANNEL-MAJOR: uint array [pair=c/2][b][t][h][w], pair stride 262144 uints.
#define NELEM 16777216

typedef _Float16 f16x8 __attribute__((ext_vector_type(8)));
typedef _Float16 h2v  __attribute__((ext_vector_type(2)));
typedef float f32x4 __attribute__((ext_vector_type(4)));

// packed f16 fma: tap from SGPR (VOP3P allows 1 SGPR source)
static __device__ __forceinline__ void pk_fma_sv(uint& d, uint a_s, uint b_v) {
    asm("v_pk_fma_f16 %0, %1, %2, %0" : "+v"(d) : "s"(a_s), "v"(b_v));
}
// packed f16 fma: tap from VGPR
static __device__ __forceinline__ void pk_fma_vv(uint& d, uint a_v, uint b_v) {
    asm("v_pk_fma_f16 %0, %1, %2, %0" : "+v"(d) : "v"(a_v), "v"(b_v));
}

// ---------------- fused dual projection GEMM (MFMA f16, channel-major out) ----------------
__global__ __launch_bounds__(256) void proj2_kernel(
    const float* __restrict__ x,
    const float* __restrict__ wg, const float* __restrict__ bg,
    const float* __restrict__ wh, const float* __restrict__ bh,
    uint* __restrict__ pg, uint* __restrict__ ph)
{
    __shared__ __align__(16) _Float16 sX[128 * 64];
    __shared__ __align__(16) _Float16 sWT[2][64 * 64];
    const int tid = threadIdx.x;
    const int row0 = (int)blockIdx.x * 128;

    #pragma unroll
    for (int kci = 0; kci < 4; ++kci) {
        const int chunk = tid + kci * 256;
        const int r = chunk >> 3, q = chunk & 7;
        const float* gp = x + (long long)(row0 + r) * 64 + q * 8;
        const float4 v0 = *reinterpret_cast<const float4*>(gp);
        const float4 v1 = *reinterpret_cast<const float4*>(gp + 4);
        f16x8 hv;
        hv[0] = (_Float16)v0.x; hv[1] = (_Float16)v0.y; hv[2] = (_Float16)v0.z; hv[3] = (_Float16)v0.w;
        hv[4] = (_Float16)v1.x; hv[5] = (_Float16)v1.y; hv[6] = (_Float16)v1.z; hv[7] = (_Float16)v1.w;
        *reinterpret_cast<f16x8*>(&sX[r * 64 + ((q ^ (r & 7)) * 8)]) = hv;
    }
    {
        const int d = tid & 63;
        const int cb = (tid >> 6) * 16;
        #pragma unroll
        for (int i = 0; i < 16; ++i) {
            const int c = cb + i;
            const int off = d * 64 + (((c >> 3) ^ (d & 7)) * 8) + (c & 7);
            sWT[0][off] = (_Float16)wg[c * 64 + d];
            sWT[1][off] = (_Float16)wh[c * 64 + d];
        }
    }
    __syncthreads();

    const int wv = tid >> 6, lm = tid & 15, lg = (tid & 63) >> 4;
    f16x8 bf[2][4][2];
    #pragma unroll
    for (int nt = 0; nt < 4; ++nt) {
        const int d = nt * 16 + lm;
        #pragma unroll
        for (int s = 0; s < 2; ++s) {
            const int off = d * 64 + (((s * 4 + lg) ^ (d & 7)) * 8);
            bf[0][nt][s] = *reinterpret_cast<const f16x8*>(&sWT[0][off]);
            bf[1][nt][s] = *reinterpret_cast<const f16x8*>(&sWT[1][off]);
        }
    }
    f32x4 acc[2][2][4];
    #pragma unroll
    for (int m = 0; m < 2; ++m)
        #pragma unroll
        for (int mt = 0; mt < 2; ++mt)
            #pragma unroll
            for (int nt = 0; nt < 4; ++nt)
                acc[m][mt][nt] = (f32x4){0.f, 0.f, 0.f, 0.f};

    #pragma unroll
    for (int mt = 0; mt < 2; ++mt) {
        const int r = wv * 32 + mt * 16 + lm;
        const f16x8 a0 = *reinterpret_cast<const f16x8*>(&sX[r * 64 + ((lg ^ (r & 7)) * 8)]);
        const f16x8 a1 = *reinterpret_cast<const f16x8*>(&sX[r * 64 + (((4 + lg) ^ (r & 7)) * 8)]);
        #pragma unroll
        for (int nt = 0; nt < 4; ++nt) {
            acc[0][mt][nt] = __builtin_amdgcn_mfma_f32_16x16x32_f16(a0, bf[0][nt][0], acc[0][mt][nt], 0, 0, 0);
            acc[0][mt][nt] = __builtin_amdgcn_mfma_f32_16x16x32_f16(a1, bf[0][nt][1], acc[0][mt][nt], 0, 0, 0);
            acc[1][mt][nt] = __builtin_amdgcn_mfma_f32_16x16x32_f16(a0, bf[1][nt][0], acc[1][mt][nt], 0, 0, 0);
            acc[1][mt][nt] = __builtin_amdgcn_mfma_f32_16x16x32_f16(a1, bf[1][nt][1], acc[1][mt][nt], 0, 0, 0);
        }
    }
    // epilogue: pair lanes (lm, lm^1) via shfl, even lane stores uint4 (4 rows) channel-major
    #pragma unroll
    for (int nt = 0; nt < 4; ++nt) {
        const int col = nt * 16 + lm;
        const int pr  = col >> 1;
        const float bgv = bg[col], bhv = bh[col];
        #pragma unroll
        for (int mt = 0; mt < 2; ++mt) {
            const int rb = row0 + wv * 32 + mt * 16 + lg * 4;
            uint pk0[4], pk1[4];
            #pragma unroll
            for (int i = 0; i < 4; ++i) {
                const float v0 = acc[0][mt][nt][i] + bgv;
                const float p0 = __shfl_xor(v0, 1);
                const float v1 = acc[1][mt][nt][i] + bhv;
                const float p1 = __shfl_xor(v1, 1);
                h2v a, c;
                a[0] = (_Float16)((lm & 1) ? p0 : v0); a[1] = (_Float16)((lm & 1) ? v0 : p0);
                c[0] = (_Float16)((lm & 1) ? p1 : v1); c[1] = (_Float16)((lm & 1) ? v1 : p1);
                pk0[i] = __builtin_bit_cast(uint, a);
                pk1[i] = __builtin_bit_cast(uint, c);
            }
            if (!(lm & 1)) {
                *reinterpret_cast<uint4*>(pg + pr * 262144 + rb) = make_uint4(pk0[0], pk0[1], pk0[2], pk0[3]);
                *reinterpret_cast<uint4*>(ph + pr * 262144 + rb) = make_uint4(pk1[0], pk1[1], pk1[2], pk1[3]);
            }
        }
    }
}

// ---------------- tap pre-convert: f32 kernels -> packed f16 pair table ----------------
// taps[((mat*32 + p)*35 + kt*7+kh)*8 + kw], kw=7 zero-padded
__global__ __launch_bounds__(256) void tapconv_kernel(
    const float* __restrict__ gk, const float* __restrict__ hk, uint* __restrict__ taps)
{
    const int i = blockIdx.x * 256 + threadIdx.x;   // [0, 17920)
    if (i >= 17920) return;
    const int kw = i & 7;
    int r = i >> 3;
    const int kth = r % 35;  r /= 35;
    const int p = r & 31;
    const int mat = r >> 5;
    if (kw >= 7) { taps[i] = 0u; return; }
    const float* K = mat ? hk : gk;
    const int tap = kth * 7 + kw;
    h2v hv;
    hv[0] = (_Float16)K[(2 * p) * 245 + tap];
    hv[1] = (_Float16)K[(2 * p + 1) * 245 + tap];
    taps[i] = __builtin_bit_cast(uint, hv);
}

// ---------------- depthwise circular 3D conv: LDS-free, 2-t blocked, channel-major ----------------
// Wave = one channel-pair x one 32x32 tile x TWO consecutive t outputs (t0, t0+1).
// 6 input planes (t0-2 .. t0+3) serve both outputs: row loads drop 300 -> 180 b128/lane,
// and each loaded row feeds two tap-sets (VMEM gap halves vs r10).
// Plane e (tin = t0-2+e): out t0 uses tap-row kt0 = 4-e (fresh SGPR set kvS, "s" operand);
// out t0+1 uses tap-row kt1 = 5-e (= previous kvS, copied to VGPR set kvV, "v" operand).
// Taps stay uniform scalar loads; rows read directly from global (r10-proven). No LDS.
__global__ __launch_bounds__(256) void conv3d_dual_kernel(
    const uint* __restrict__ inG, uint* __restrict__ outG,
    const uint* __restrict__ inH, uint* __restrict__ outH,
    const uint* __restrict__ taps)
{
    const int bid = (int)blockIdx.x;                // 0..2047
    const int l = ((bid & 7) << 8) | (bid >> 3);    // chunked XCD swizzle
    const int tile = l & 3;
    const int pgrp = (l >> 2) & 7;
    const int tp   = (l >> 5) & 15;
    const int b    = (l >> 9) & 1;
    const int mat  = (l >> 10) & 1;
    const int wave = threadIdx.x >> 6;
    const int lane = threadIdx.x & 63;
    const int h0 = (tile >> 1) * 32, w0 = (tile & 1) * 32;
    const int t0 = tp * 2;
    const int pair = pgrp * 4 + wave;

    const uint* in = mat ? inH : inG;
    uint* out      = mat ? outH : outG;

    const int iy = lane >> 3, ix = lane & 7;

    // wave-uniform SGPR bases
    const int tapOff = __builtin_amdgcn_readfirstlane((mat * 32 + pair) * 280);
    const uint* tb = taps + tapOff;
    const int pbOff = __builtin_amdgcn_readfirstlane(pair * 262144 + b * 131072);

    // hoisted per-lane offsets (plane-invariant)
    int colu[3];
    #pragma unroll
    for (int m = 0; m < 3; ++m) colu[m] = (w0 + 4 * ix - 4 + 4 * m) & 63;
    int rowu[10];
    #pragma unroll
    for (int rr = 0; rr < 10; ++rr) rowu[rr] = ((h0 - 3 + 4 * iy + rr) & 63) * 64;

    uint tot0[4][4], tot1[4][4];
    #pragma unroll
    for (int o = 0; o < 4; ++o)
        #pragma unroll
        for (int j = 0; j < 4; ++j) { tot0[o][j] = 0u; tot1[o][j] = 0u; }

    uint kvS[56];   // current tap-row set (uniform -> SGPRs)
    uint kvV[56];   // previous tap-row set (VGPR copy, "v" operand)

    #pragma unroll 1
    for (int e = 0; e < 6; ++e) {
        // promote previous kvS to VGPR set for out1 (tap-row kt1 = 5-e)
        if (e > 0) {
            #pragma unroll
            for (int i = 0; i < 56; ++i) kvV[i] = kvS[i];
        }
        // load fresh tap-row kt0 = 4-e for out0 (uniform scalar loads)
        if (e <= 4) {
            const uint* tkt = tb + (4 - e) * 56;
            #pragma unroll
            for (int i = 0; i < 56; ++i) kvS[i] = tkt[i];
        }

        const int tin = (t0 - 2 + e) & 31;
        const uint* pin = in + pbOff + tin * 4096;   // SGPR plane base

        #pragma unroll
        for (int rr = 0; rr < 10; ++rr) {
            uint row[12];
            #pragma unroll
            for (int m = 0; m < 3; ++m) {
                const uint4 v = *reinterpret_cast<const uint4*>(pin + rowu[rr] + colu[m]);
                row[4 * m]     = v.x; row[4 * m + 1] = v.y;
                row[4 * m + 2] = v.z; row[4 * m + 3] = v.w;
            }
            if (e <= 4) {                            // out t0, taps kvS (SGPR)
                #pragma unroll
                for (int kw = 0; kw < 7; ++kw)
                    #pragma unroll
                    for (int o = 0; o < 4; ++o) {
                        const int kh = o + 6 - rr;
                        if (kh < 0 || kh > 6) continue;
                        #pragma unroll
                        for (int j = 0; j < 4; ++j)
                            pk_fma_sv(tot0[o][j], kvS[kh * 8 + kw], row[j + 7 - kw]);
                    }
            }
            if (e >= 1) {                            // out t0+1, taps kvV (VGPR)
                #pragma unroll
                for (int kw = 0; kw < 7; ++kw)
                    #pragma unroll
                    for (int o = 0; o < 4; ++o) {
                        const int kh = o + 6 - rr;
                        if (kh < 0 || kh > 6) continue;
                        #pragma unroll
                        for (int j = 0; j < 4; ++j)
                            pk_fma_vv(tot1[o][j], kvV[kh * 8 + kw], row[j + 7 - kw]);
                    }
            }
        }
    }

    uint* ob0 = out + pair * 262144 + (b * 32 + t0) * 4096;
    #pragma unroll
    for (int o = 0; o < 4; ++o) {
        *reinterpret_cast<uint4*>(ob0 + (h0 + 4 * iy + o) * 64 + (w0 + 4 * ix)) =
            make_uint4(tot0[o][0], tot0[o][1], tot0[o][2], tot0[o][3]);
        *reinterpret_cast<uint4*>(ob0 + 4096 + (h0 + 4 * iy + o) * 64 + (w0 + 4 * ix)) =
            make_uint4(tot1[o][0], tot1[o][1], tot1[o][2], tot1[o][3]);
    }
}

// ---------------- minGRU scan over T (f32 math, channel-major h2 I/O) ----------------
__global__ __launch_bounds__(256) void scan_kernel(
    const uint* __restrict__ gs, const uint* __restrict__ hs, uint* __restrict__ hout)
{
    const int tid = blockIdx.x * 256 + threadIdx.x;    // 0..262143
    const int base = (tid >> 12) * 131072 + (tid & 4095);
    float h0 = 0.f, h1 = 0.f;
    for (int t = 0; t < 32; ++t) {
        const int a = base + t * 4096;
        const float2 g  = __half22float2(__builtin_bit_cast(__half2, gs[a]));
        const float2 hv = __half22float2(__builtin_bit_cast(__half2, hs[a]));
        const float z0 = 1.f / (1.f + __expf(-g.x));
        const float z1 = 1.f / (1.f + __expf(-g.y));
        h0 = fmaf(1.f - z0, h0, z0 * fmaf(hv.x, hv.x, 1e-6f));
        h1 = fmaf(1.f - z1, h1, z1 * fmaf(hv.y, hv.y, 1e-6f));
        hout[a] = __builtin_bit_cast(uint, __floats2half2_rn(h0, h1));
    }
}

// ---------------- output GEMM (MFMA f16, channel-major in, f32 row-major out) ----------------
__global__ __launch_bounds__(256) void outgemm_kernel(
    const uint* __restrict__ hin, const float* __restrict__ w,
    const float* __restrict__ bias, float* __restrict__ out)
{
    __shared__ __align__(16) uint sXu[128 * 36];        // rows x 32 pairs (stride 36: 16B-aligned)
    __shared__ __align__(16) _Float16 sWT[64 * 64];
    const int tid = threadIdx.x;
    const int row0 = (int)blockIdx.x * 128;

    {   // stage 128 rows x 32 pairs from channel-major
        const int pr = tid >> 3, k = tid & 7;
        const uint* src = hin + pr * 262144 + row0 + k * 16;
        #pragma unroll
        for (int q = 0; q < 4; ++q) {
            const uint4 v = *reinterpret_cast<const uint4*>(src + q * 4);
            sXu[(k * 16 + q * 4 + 0) * 36 + pr] = v.x;
            sXu[(k * 16 + q * 4 + 1) * 36 + pr] = v.y;
            sXu[(k * 16 + q * 4 + 2) * 36 + pr] = v.z;
            sXu[(k * 16 + q * 4 + 3) * 36 + pr] = v.w;
        }
    }
    {
        const int d = tid & 63;
        const int cb = (tid >> 6) * 16;
        #pragma unroll
        for (int i = 0; i < 16; ++i) {
            const int c = cb + i;
            sWT[d * 64 + (((c >> 3) ^ (d & 7)) * 8) + (c & 7)] = (_Float16)w[c * 64 + d];
        }
    }
    __syncthreads();

    const int wv = tid >> 6, lm = tid & 15, lg = (tid & 63) >> 4;
    f16x8 bf[4][2];
    #pragma unroll
    for (int nt = 0; nt < 4; ++nt) {
        const int d = nt * 16 + lm;
        #pragma unroll
        for (int s = 0; s < 2; ++s)
            bf[nt][s] = *reinterpret_cast<const f16x8*>(&sWT[d * 64 + (((s * 4 + lg) ^ (d & 7)) * 8)]);
    }
    f32x4 acc[2][4];
    #pragma unroll
    for (int mt = 0; mt < 2; ++mt)
        #pragma unroll
        for (int nt = 0; nt < 4; ++nt)
            acc[mt][nt] = (f32x4){0.f, 0.f, 0.f, 0.f};

    #pragma unroll
    for (int mt = 0; mt < 2; ++mt) {
        const int r = wv * 32 + mt * 16 + lm;
        const f16x8 a0 = *reinterpret_cast<const f16x8*>(&sXu[r * 36 + lg * 4]);
        const f16x8 a1 = *reinterpret_cast<const f16x8*>(&sXu[r * 36 + 16 + lg * 4]);
        #pragma unroll
        for (int nt = 0; nt < 4; ++nt) {
            acc[mt][nt] = __builtin_amdgcn_mfma_f32_16x16x32_f16(a0, bf[nt][0], acc[mt][nt], 0, 0, 0);
            acc[mt][nt] = __builtin_amdgcn_mfma_f32_16x16x32_f16(a1, bf[nt][1], acc[mt][nt], 0, 0, 0);
        }
    }
    #pragma unroll
    for (int nt = 0; nt < 4; ++nt) {
        const int col = nt * 16 + lm;
        const float bv = bias[col];
        #pragma unroll
        for (int mt = 0; mt < 2; ++mt) {
            const long long rb = row0 + wv * 32 + mt * 16 + lg * 4;
            #pragma unroll
            for (int i = 0; i < 4; ++i)
                out[(rb + i) * 64 + col] = acc[mt][nt][i] + bv;
        }
    }
}

extern "C" void kernel_launch(void* const* d_in, const int* in_sizes, int n_in,
                              void* d_out, int out_size, void* d_ws, size_t ws_size,
                              hipStream_t stream)
{
    const float* x  = (const float*)d_in[0];
    const float* gw = (const float*)d_in[1];
    const float* gb = (const float*)d_in[2];
    const float* hw = (const float*)d_in[3];
    const float* hb = (const float*)d_in[4];
    const float* gk = (const float*)d_in[5];
    const float* hk = (const float*)d_in[6];
    const float* ow = (const float*)d_in[7];
    const float* ob = (const float*)d_in[8];

    uint* W1 = (uint*)d_ws;                  // 33.5 MB each (channel-major h2)
    uint* W2 = W1 + NELEM / 2;
    uint* W3 = W2 + NELEM / 2;
    uint* taps = W3 + NELEM / 2;             // 71.7 KB tap table
    uint* Dsc = (uint*)d_out;                // hidden_spatial scratch (first 33.5MB of d_out)

    // 0) tap table
    tapconv_kernel<<<70, 256, 0, stream>>>(gk, hk, taps);
    // 1) proj: x -> W1 (gate_proj cm), W2 (hidden_proj cm)
    proj2_kernel<<<2048, 256, 0, stream>>>(x, gw, gb, hw, hb, W1, W2);
    // 2+3) dual conv (LDS-free, 2-t blocked): W1 -> W3 (gate_sp), W2 -> Dsc (hidden_sp)
    conv3d_dual_kernel<<<2048, 256, 0, stream>>>(W1, W3, W2, Dsc, taps);
    // 4) scan: (W3, Dsc) -> W1 (h, cm)
    scan_kernel<<<1024, 256, 0, stream>>>(W3, Dsc, W1);
    // 5) out GEMM: W1 -> d_out (f32 row-major, overwrites scratch)
    outgemm_kernel<<<2048, 256, 0, stream>>>(W1, ow, ob, (float*)d_out);
}

// Round 14
// 207.262 us; speedup vs baseline: 1.1731x; 1.1530x over previous
//
#include <hip/hip_runtime.h>
#include <hip/hip_fp16.h>

// Problem constants: B=2, T=32, H=64, W=64, C=64, KT=5, K=7. Circular dims pow2 -> & masks.
// Intermediates are CHANNEL-MAJOR: uint array [pair=c/2][b][t][h][w], pair stride 262144 uints.
#define NELEM 16777216

typedef _Float16 f16x8 __attribute__((ext_vector_type(8)));
typedef _Float16 h2v  __attribute__((ext_vector_type(2)));
typedef float f32x4 __attribute__((ext_vector_type(4)));

// packed f16 fma, tap in SGPR (VOP3P allows 1 SGPR source)
static __device__ __forceinline__ void pk_fma_sv(uint& d, uint a_s, uint b_v) {
    asm("v_pk_fma_f16 %0, %1, %2, %0" : "+v"(d) : "s"(a_s), "v"(b_v));
}

// ---------------- fused dual projection GEMM (MFMA f16, channel-major out) ----------------
__global__ __launch_bounds__(256) void proj2_kernel(
    const float* __restrict__ x,
    const float* __restrict__ wg, const float* __restrict__ bg,
    const float* __restrict__ wh, const float* __restrict__ bh,
    uint* __restrict__ pg, uint* __restrict__ ph)
{
    __shared__ __align__(16) _Float16 sX[128 * 64];
    __shared__ __align__(16) _Float16 sWT[2][64 * 64];
    const int tid = threadIdx.x;
    const int row0 = (int)blockIdx.x * 128;

    #pragma unroll
    for (int kci = 0; kci < 4; ++kci) {
        const int chunk = tid + kci * 256;
        const int r = chunk >> 3, q = chunk & 7;
        const float* gp = x + (long long)(row0 + r) * 64 + q * 8;
        const float4 v0 = *reinterpret_cast<const float4*>(gp);
        const float4 v1 = *reinterpret_cast<const float4*>(gp + 4);
        f16x8 hv;
        hv[0] = (_Float16)v0.x; hv[1] = (_Float16)v0.y; hv[2] = (_Float16)v0.z; hv[3] = (_Float16)v0.w;
        hv[4] = (_Float16)v1.x; hv[5] = (_Float16)v1.y; hv[6] = (_Float16)v1.z; hv[7] = (_Float16)v1.w;
        *reinterpret_cast<f16x8*>(&sX[r * 64 + ((q ^ (r & 7)) * 8)]) = hv;
    }
    {
        const int d = tid & 63;
        const int cb = (tid >> 6) * 16;
        #pragma unroll
        for (int i = 0; i < 16; ++i) {
            const int c = cb + i;
            const int off = d * 64 + (((c >> 3) ^ (d & 7)) * 8) + (c & 7);
            sWT[0][off] = (_Float16)wg[c * 64 + d];
            sWT[1][off] = (_Float16)wh[c * 64 + d];
        }
    }
    __syncthreads();

    const int wv = tid >> 6, lm = tid & 15, lg = (tid & 63) >> 4;
    f16x8 bf[2][4][2];
    #pragma unroll
    for (int nt = 0; nt < 4; ++nt) {
        const int d = nt * 16 + lm;
        #pragma unroll
        for (int s = 0; s < 2; ++s) {
            const int off = d * 64 + (((s * 4 + lg) ^ (d & 7)) * 8);
            bf[0][nt][s] = *reinterpret_cast<const f16x8*>(&sWT[0][off]);
            bf[1][nt][s] = *reinterpret_cast<const f16x8*>(&sWT[1][off]);
        }
    }
    f32x4 acc[2][2][4];
    #pragma unroll
    for (int m = 0; m < 2; ++m)
        #pragma unroll
        for (int mt = 0; mt < 2; ++mt)
            #pragma unroll
            for (int nt = 0; nt < 4; ++nt)
                acc[m][mt][nt] = (f32x4){0.f, 0.f, 0.f, 0.f};

    #pragma unroll
    for (int mt = 0; mt < 2; ++mt) {
        const int r = wv * 32 + mt * 16 + lm;
        const f16x8 a0 = *reinterpret_cast<const f16x8*>(&sX[r * 64 + ((lg ^ (r & 7)) * 8)]);
        const f16x8 a1 = *reinterpret_cast<const f16x8*>(&sX[r * 64 + (((4 + lg) ^ (r & 7)) * 8)]);
        #pragma unroll
        for (int nt = 0; nt < 4; ++nt) {
            acc[0][mt][nt] = __builtin_amdgcn_mfma_f32_16x16x32_f16(a0, bf[0][nt][0], acc[0][mt][nt], 0, 0, 0);
            acc[0][mt][nt] = __builtin_amdgcn_mfma_f32_16x16x32_f16(a1, bf[0][nt][1], acc[0][mt][nt], 0, 0, 0);
            acc[1][mt][nt] = __builtin_amdgcn_mfma_f32_16x16x32_f16(a0, bf[1][nt][0], acc[1][mt][nt], 0, 0, 0);
            acc[1][mt][nt] = __builtin_amdgcn_mfma_f32_16x16x32_f16(a1, bf[1][nt][1], acc[1][mt][nt], 0, 0, 0);
        }
    }
    // epilogue: pair lanes (lm, lm^1) via shfl, even lane stores uint4 (4 rows) channel-major
    #pragma unroll
    for (int nt = 0; nt < 4; ++nt) {
        const int col = nt * 16 + lm;
        const int pr  = col >> 1;
        const float bgv = bg[col], bhv = bh[col];
        #pragma unroll
        for (int mt = 0; mt < 2; ++mt) {
            const int rb = row0 + wv * 32 + mt * 16 + lg * 4;
            uint pk0[4], pk1[4];
            #pragma unroll
            for (int i = 0; i < 4; ++i) {
                const float v0 = acc[0][mt][nt][i] + bgv;
                const float p0 = __shfl_xor(v0, 1);
                const float v1 = acc[1][mt][nt][i] + bhv;
                const float p1 = __shfl_xor(v1, 1);
                h2v a, c;
                a[0] = (_Float16)((lm & 1) ? p0 : v0); a[1] = (_Float16)((lm & 1) ? v0 : p0);
                c[0] = (_Float16)((lm & 1) ? p1 : v1); c[1] = (_Float16)((lm & 1) ? v1 : p1);
                pk0[i] = __builtin_bit_cast(uint, a);
                pk1[i] = __builtin_bit_cast(uint, c);
            }
            if (!(lm & 1)) {
                *reinterpret_cast<uint4*>(pg + pr * 262144 + rb) = make_uint4(pk0[0], pk0[1], pk0[2], pk0[3]);
                *reinterpret_cast<uint4*>(ph + pr * 262144 + rb) = make_uint4(pk1[0], pk1[1], pk1[2], pk1[3]);
            }
        }
    }
}

// ---------------- tap pre-convert: f32 kernels -> packed f16 pair table ----------------
// taps[((mat*32 + p)*35 + kt*7+kh)*8 + kw], kw=7 zero-padded
__global__ __launch_bounds__(256) void tapconv_kernel(
    const float* __restrict__ gk, const float* __restrict__ hk, uint* __restrict__ taps)
{
    const int i = blockIdx.x * 256 + threadIdx.x;   // [0, 17920)
    if (i >= 17920) return;
    const int kw = i & 7;
    int r = i >> 3;
    const int kth = r % 35;  r /= 35;
    const int p = r & 31;
    const int mat = r >> 5;
    if (kw >= 7) { taps[i] = 0u; return; }
    const float* K = mat ? hk : gk;
    const int tap = kth * 7 + kw;
    h2v hv;
    hv[0] = (_Float16)K[(2 * p) * 245 + tap];
    hv[1] = (_Float16)K[(2 * p + 1) * 245 + tap];
    taps[i] = __builtin_bit_cast(uint, hv);
}

// ---------------- depthwise circular 3D conv: LDS-FREE, channel-major (r10 optimum) ----------------
// Wave = one channel-pair over one 32x32 tile; lane (iy,ix) computes 4h x 4w.
// Input window read DIRECTLY from global (SGPR plane base + per-lane voffset); 8-lane
// groups are 128B-contiguous; circular W-wrap (&63 on 4-aligned cols) never splits a uint4.
// Taps: wave-uniform scalar loads -> SGPRs, pk_fma takes tap as SGPR src0.
// No LDS, no barriers. Empirical optimum of rounds 9-13 (LDS slab, 2-t blocking, explicit
// pipelining, occupancy attrs all measured worse or null).
__global__ __launch_bounds__(256) void conv3d_dual_kernel(
    const uint* __restrict__ inG, uint* __restrict__ outG,
    const uint* __restrict__ inH, uint* __restrict__ outH,
    const uint* __restrict__ taps)
{
    const int bid = (int)blockIdx.x;                // 0..4095
    const int l = ((bid & 7) << 9) | (bid >> 3);    // chunked XCD swizzle
    const int tile = l & 3;
    const int pgrp = (l >> 2) & 7;
    const int t    = (l >> 5) & 31;
    const int b    = (l >> 10) & 1;
    const int mat  = (l >> 11) & 1;
    const int wave = threadIdx.x >> 6;
    const int lane = threadIdx.x & 63;
    const int h0 = (tile >> 1) * 32, w0 = (tile & 1) * 32;
    const int pair = pgrp * 4 + wave;

    const uint* in = mat ? inH : inG;
    uint* out      = mat ? outH : outG;

    const int iy = lane >> 3, ix = lane & 7;

    // wave-uniform SGPR bases
    const int tapOff = __builtin_amdgcn_readfirstlane((mat * 32 + pair) * 280);
    const uint* tb = taps + tapOff;
    const int pbOff = __builtin_amdgcn_readfirstlane(pair * 262144 + b * 131072);

    // per-lane window chunk columns (uint idx, 4-aligned, circular)
    int colu[3];
    #pragma unroll
    for (int m = 0; m < 3; ++m) colu[m] = (w0 + 4 * ix - 4 + 4 * m) & 63;

    uint tot[4][4];
    #pragma unroll
    for (int o = 0; o < 4; ++o)
        #pragma unroll
        for (int j = 0; j < 4; ++j) tot[o][j] = 0u;

    #pragma unroll 1
    for (int kt = 0; kt < 5; ++kt) {
        const int tin = (t - kt + 2) & 31;
        const uint* pin = in + pbOff + tin * 4096;      // SGPR base
        const uint* tkt = tb + kt * 56;

        uint kv[7][8];                                  // SGPR tap block (uniform loads)
        #pragma unroll
        for (int kh = 6; kh >= 5; --kh)                 // prologue: kh used at rr=0,1
            #pragma unroll
            for (int i2 = 0; i2 < 8; ++i2) kv[kh][i2] = tkt[kh * 8 + i2];

        #pragma unroll
        for (int rr = 0; rr < 10; ++rr) {
            if (rr <= 4) {                              // prefetch kh=4-rr (first use at rr+2)
                const int kh = 4 - rr;
                #pragma unroll
                for (int i2 = 0; i2 < 8; ++i2) kv[kh][i2] = tkt[kh * 8 + i2];
            }
            const int gh = (h0 - 3 + 4 * iy + rr) & 63;
            const int rowu = gh * 64;
            uint row[12];
            #pragma unroll
            for (int m = 0; m < 3; ++m) {
                const uint4 v = *reinterpret_cast<const uint4*>(pin + rowu + colu[m]);
                row[4 * m]     = v.x; row[4 * m + 1] = v.y;
                row[4 * m + 2] = v.z; row[4 * m + 3] = v.w;
            }
            #pragma unroll
            for (int o = 0; o < 4; ++o) {
                const int kh = o + 6 - rr;
                if (kh < 0 || kh > 6) continue;
                #pragma unroll
                for (int kw = 0; kw < 7; ++kw)
                    #pragma unroll
                    for (int j = 0; j < 4; ++j)
                        pk_fma_sv(tot[o][j], kv[kh][kw], row[j + 7 - kw]);
            }
        }
    }

    uint* ob = out + pair * 262144 + (b * 32 + t) * 4096;
    #pragma unroll
    for (int o = 0; o < 4; ++o)
        *reinterpret_cast<uint4*>(ob + (h0 + 4 * iy + o) * 64 + (w0 + 4 * ix)) =
            make_uint4(tot[o][0], tot[o][1], tot[o][2], tot[o][3]);
}

// ---------------- minGRU scan over T (f32 math, channel-major h2 I/O) ----------------
__global__ __launch_bounds__(256) void scan_kernel(
    const uint* __restrict__ gs, const uint* __restrict__ hs, uint* __restrict__ hout)
{
    const int tid = blockIdx.x * 256 + threadIdx.x;    // 0..262143
    const int base = (tid >> 12) * 131072 + (tid & 4095);
    float h0 = 0.f, h1 = 0.f;
    for (int t = 0; t < 32; ++t) {
        const int a = base + t * 4096;
        const float2 g  = __half22float2(__builtin_bit_cast(__half2, gs[a]));
        const float2 hv = __half22float2(__builtin_bit_cast(__half2, hs[a]));
        const float z0 = 1.f / (1.f + __expf(-g.x));
        const float z1 = 1.f / (1.f + __expf(-g.y));
        h0 = fmaf(1.f - z0, h0, z0 * fmaf(hv.x, hv.x, 1e-6f));
        h1 = fmaf(1.f - z1, h1, z1 * fmaf(hv.y, hv.y, 1e-6f));
        hout[a] = __builtin_bit_cast(uint, __floats2half2_rn(h0, h1));
    }
}

// ---------------- output GEMM (MFMA f16, channel-major in, f32 row-major out) ----------------
__global__ __launch_bounds__(256) void outgemm_kernel(
    const uint* __restrict__ hin, const float* __restrict__ w,
    const float* __restrict__ bias, float* __restrict__ out)
{
    __shared__ __align__(16) uint sXu[128 * 36];        // rows x 32 pairs (stride 36: 16B-aligned)
    __shared__ __align__(16) _Float16 sWT[64 * 64];
    const int tid = threadIdx.x;
    const int row0 = (int)blockIdx.x * 128;

    {   // stage 128 rows x 32 pairs from channel-major
        const int pr = tid >> 3, k = tid & 7;
        const uint* src = hin + pr * 262144 + row0 + k * 16;
        #pragma unroll
        for (int q = 0; q < 4; ++q) {
            const uint4 v = *reinterpret_cast<const uint4*>(src + q * 4);
            sXu[(k * 16 + q * 4 + 0) * 36 + pr] = v.x;
            sXu[(k * 16 + q * 4 + 1) * 36 + pr] = v.y;
            sXu[(k * 16 + q * 4 + 2) * 36 + pr] = v.z;
            sXu[(k * 16 + q * 4 + 3) * 36 + pr] = v.w;
        }
    }
    {
        const int d = tid & 63;
        const int cb = (tid >> 6) * 16;
        #pragma unroll
        for (int i = 0; i < 16; ++i) {
            const int c = cb + i;
            sWT[d * 64 + (((c >> 3) ^ (d & 7)) * 8) + (c & 7)] = (_Float16)w[c * 64 + d];
        }
    }
    __syncthreads();

    const int wv = tid >> 6, lm = tid & 15, lg = (tid & 63) >> 4;
    f16x8 bf[4][2];
    #pragma unroll
    for (int nt = 0; nt < 4; ++nt) {
        const int d = nt * 16 + lm;
        #pragma unroll
        for (int s = 0; s < 2; ++s)
            bf[nt][s] = *reinterpret_cast<const f16x8*>(&sWT[d * 64 + (((s * 4 + lg) ^ (d & 7)) * 8)]);
    }
    f32x4 acc[2][4];
    #pragma unroll
    for (int mt = 0; mt < 2; ++mt)
        #pragma unroll
        for (int nt = 0; nt < 4; ++nt)
            acc[mt][nt] = (f32x4){0.f, 0.f, 0.f, 0.f};

    #pragma unroll
    for (int mt = 0; mt < 2; ++mt) {
        const int r = wv * 32 + mt * 16 + lm;
        const f16x8 a0 = *reinterpret_cast<const f16x8*>(&sXu[r * 36 + lg * 4]);
        const f16x8 a1 = *reinterpret_cast<const f16x8*>(&sXu[r * 36 + 16 + lg * 4]);
        #pragma unroll
        for (int nt = 0; nt < 4; ++nt) {
            acc[mt][nt] = __builtin_amdgcn_mfma_f32_16x16x32_f16(a0, bf[nt][0], acc[mt][nt], 0, 0, 0);
            acc[mt][nt] = __builtin_amdgcn_mfma_f32_16x16x32_f16(a1, bf[nt][1], acc[mt][nt], 0, 0, 0);
        }
    }
    #pragma unroll
    for (int nt = 0; nt < 4; ++nt) {
        const int col = nt * 16 + lm;
        const float bv = bias[col];
        #pragma unroll
        for (int mt = 0; mt < 2; ++mt) {
            const long long rb = row0 + wv * 32 + mt * 16 + lg * 4;
            #pragma unroll
            for (int i = 0; i < 4; ++i)
                out[(rb + i) * 64 + col] = acc[mt][nt][i] + bv;
        }
    }
}

extern "C" void kernel_launch(void* const* d_in, const int* in_sizes, int n_in,
                              void* d_out, int out_size, void* d_ws, size_t ws_size,
                              hipStream_t stream)
{
    const float* x  = (const float*)d_in[0];
    const float* gw = (const float*)d_in[1];
    const float* gb = (const float*)d_in[2];
    const float* hw = (const float*)d_in[3];
    const float* hb = (const float*)d_in[4];
    const float* gk = (const float*)d_in[5];
    const float* hk = (const float*)d_in[6];
    const float* ow = (const float*)d_in[7];
    const float* ob = (const float*)d_in[8];

    uint* W1 = (uint*)d_ws;                  // 33.5 MB each (channel-major h2)
    uint* W2 = W1 + NELEM / 2;
    uint* W3 = W2 + NELEM / 2;
    uint* taps = W3 + NELEM / 2;             // 71.7 KB tap table
    uint* Dsc = (uint*)d_out;                // hidden_spatial scratch (first 33.5MB of d_out)

    // 0) tap table
    tapconv_kernel<<<70, 256, 0, stream>>>(gk, hk, taps);
    // 1) proj: x -> W1 (gate_proj cm), W2 (hidden_proj cm)
    proj2_kernel<<<2048, 256, 0, stream>>>(x, gw, gb, hw, hb, W1, W2);
    // 2+3) dual conv (LDS-free): W1 -> W3 (gate_sp), W2 -> Dsc (hidden_sp)
    conv3d_dual_kernel<<<4096, 256, 0, stream>>>(W1, W3, W2, Dsc, taps);
    // 4) scan: (W3, Dsc) -> W1 (h, cm)
    scan_kernel<<<1024, 256, 0, stream>>>(W3, Dsc, W1);
    // 5) out GEMM: W1 -> d_out (f32 row-major, overwrites scratch)
    outgemm_kernel<<<2048, 256, 0, stream>>>(W1, ow, ob, (float*)d_out);
}